// Round 1
// baseline (799.233 us; speedup 1.0000x reference)
//
#include <hip/hip_runtime.h>
#include <hip/hip_bf16.h>

// MACE-like GNN on MI355X. f32 baseline, VALU-bound.
// B=32, N=128, F=64, N_RBF=8, H_R=64, L=2, E=N*(N-1)=16256 per graph.

#define NN 128
#define BB 32
#define FF 64

__device__ __forceinline__ float readlane_f(float v, int lane) {
    return __int_as_float(__builtin_amdgcn_readlane(__float_as_int(v), lane));
}

// -------------------- init: s = embed[species] + glob @ glob_w ; v = 0 -----
__global__ __launch_bounds__(64) void init_kernel(
    const int* __restrict__ species, const float* __restrict__ glob,
    const float* __restrict__ embed, const float* __restrict__ glob_w,
    float* __restrict__ s, float* __restrict__ v)
{
    const int node = blockIdx.x;          // b*128 + n
    const int b = node >> 7;
    const int f = threadIdx.x;
    const int sp = species[node];
    float acc = embed[sp * FF + f];
#pragma unroll
    for (int k = 0; k < 16; ++k)
        acc = fmaf(glob[b * 16 + k], glob_w[k * FF + f], acc);
    s[node * FF + f] = acc;
    v[node * 192 + f] = 0.0f;
    v[node * 192 + 64 + f] = 0.0f;
    v[node * 192 + 128 + f] = 0.0f;
}

// -------------------- message + aggregation ------------------------------
// grid (128 receivers, 32 batch), block 256 = 4 waves.
// wave w handles hidden units h in [16w, 16w+16); lane f = channel.
// v layout: [node][d][f] (d-major for coalescing).
__global__ __launch_bounds__(256) void msg_kernel(
    const float* __restrict__ pos,     // [B][N][3]
    const float* __restrict__ s_in,    // [B][N][F]
    const float* __restrict__ v_in,    // [B][N][3][F]
    const float* __restrict__ w1,      // [8][64]   (layer slice)
    const float* __restrict__ b1,      // [64]
    const float* __restrict__ w2,      // [64][192]
    float* __restrict__ agg_s,         // [B][N][F]
    float* __restrict__ agg_v)         // [B][N][3][F]
{
    const int i = blockIdx.x;
    const int b = blockIdx.y;
    const int t = threadIdx.x;
    const int w = t >> 6;
    const int f = t & 63;
    const int k = f & 15;
    const int h = w * 16 + k;          // this lane's hidden unit

    // W2 columns for this lane's channel, this wave's 16 h-units (48 VGPR)
    float w2c[48];
#pragma unroll
    for (int kk = 0; kk < 16; ++kk) {
        const float* row = w2 + (w * 16 + kk) * 192;
        w2c[kk * 3 + 0] = row[f];
        w2c[kk * 3 + 1] = row[64 + f];
        w2c[kk * 3 + 2] = row[128 + f];
    }
    // radial MLP first-layer column for h
    float w1c[8];
#pragma unroll
    for (int r = 0; r < 8; ++r) w1c[r] = w1[r * 64 + h];
    const float b1v = b1[h];

    const float pix = pos[(b * NN + i) * 3 + 0];
    const float piy = pos[(b * NN + i) * 3 + 1];
    const float piz = pos[(b * NN + i) * 3 + 2];

    // gaussian RBF: centers linspace(0,5,8) -> spacing 5/7; width 5/8
    const float myc = (float)(f & 7) * (5.0f / 7.0f);
    const float inv2w2 = 1.0f / (2.0f * 0.625f * 0.625f);

    float accs = 0.0f, accv0 = 0.0f, accv1 = 0.0f, accv2 = 0.0f;
    const float* sb = s_in + b * NN * FF;
    const float* vb = v_in + b * NN * 192;
    const float* pb = pos + b * NN * 3;

    for (int j = 0; j < NN; ++j) {
        if (j == i) continue;
        const float dx = pix - pb[j * 3 + 0];
        const float dy = piy - pb[j * 3 + 1];
        const float dz = piz - pb[j * 3 + 2];
        const float d2 = fmaf(dx, dx, fmaf(dy, dy, fmaf(dz, dz, 1e-12f)));
        const float inv = rsqrtf(d2);
        const float dd = d2 * inv;

        // phi: lane (f&7) computes gaussian (f&7)
        const float td = dd - myc;
        const float myphi = __expf(-td * td * inv2w2);

        // hidden unit h = b1 + sum_r phi_r * W1[r][h]
        float hacc = b1v;
#pragma unroll
        for (int r = 0; r < 8; ++r)
            hacc = fmaf(readlane_f(myphi, r), w1c[r], hacc);
        // silu
        const float hval = hacc / (1.0f + __expf(-hacc));

        // partial rw for this wave's h-range
        float r1 = 0.0f, r2 = 0.0f, r3 = 0.0f;
#pragma unroll
        for (int kk = 0; kk < 16; ++kk) {
            const float hv = readlane_f(hval, kk);
            r1 = fmaf(hv, w2c[kk * 3 + 0], r1);
            r2 = fmaf(hv, w2c[kk * 3 + 1], r2);
            r3 = fmaf(hv, w2c[kk * 3 + 2], r3);
        }

        const float sj  = sb[j * FF + f];
        const float vj0 = vb[j * 192 + 0 * 64 + f];
        const float vj1 = vb[j * 192 + 1 * 64 + f];
        const float vj2 = vb[j * 192 + 2 * 64 + f];

        accs = fmaf(r1, sj, accs);
        const float r3s = r3 * sj;
        accv0 = fmaf(r2, vj0, fmaf(r3s, dx * inv, accv0));
        accv1 = fmaf(r2, vj1, fmaf(r3s, dy * inv, accv1));
        accv2 = fmaf(r2, vj2, fmaf(r3s, dz * inv, accv2));
    }

    // reduce partial-h contributions across the 4 waves
    __shared__ float red[4][256];
    red[0][t] = accs; red[1][t] = accv0; red[2][t] = accv1; red[3][t] = accv2;
    __syncthreads();
    if (w == 0) {
        const float invn = 1.0f / 127.0f;
        const float rs  = (red[0][f] + red[0][64 + f] + red[0][128 + f] + red[0][192 + f]) * invn;
        const float rv0 = (red[1][f] + red[1][64 + f] + red[1][128 + f] + red[1][192 + f]) * invn;
        const float rv1 = (red[2][f] + red[2][64 + f] + red[2][128 + f] + red[2][192 + f]) * invn;
        const float rv2 = (red[3][f] + red[3][64 + f] + red[3][128 + f] + red[3][192 + f]) * invn;
        const int node = b * NN + i;
        agg_s[node * FF + f] = rs;
        agg_v[node * 192 + 0 * 64 + f] = rv0;
        agg_v[node * 192 + 1 * 64 + f] = rv1;
        agg_v[node * 192 + 2 * 64 + f] = rv2;
    }
}

// -------------------- node update: s += agg_s@ws ; v += einsum(agg_v, wv) --
__global__ __launch_bounds__(64) void update_kernel(
    const float* __restrict__ agg_s, const float* __restrict__ agg_v,
    const float* __restrict__ ws, const float* __restrict__ wv,
    float* __restrict__ s, float* __restrict__ v)
{
    const int node = blockIdx.x;
    const int g = threadIdx.x;
    const float as  = agg_s[node * FF + g];
    const float av0 = agg_v[node * 192 + 0 * 64 + g];
    const float av1 = agg_v[node * 192 + 1 * 64 + g];
    const float av2 = agg_v[node * 192 + 2 * 64 + g];
    float ss = 0.0f, sv0 = 0.0f, sv1 = 0.0f, sv2 = 0.0f;
#pragma unroll
    for (int ff = 0; ff < 64; ++ff) {
        const float a  = readlane_f(as, ff);
        const float b0 = readlane_f(av0, ff);
        const float b1 = readlane_f(av1, ff);
        const float b2 = readlane_f(av2, ff);
        const float wsv = ws[ff * 64 + g];
        const float wvv = wv[ff * 64 + g];
        ss  = fmaf(a, wsv, ss);
        sv0 = fmaf(b0, wvv, sv0);
        sv1 = fmaf(b1, wvv, sv1);
        sv2 = fmaf(b2, wvv, sv2);
    }
    s[node * FF + g] += ss;
    v[node * 192 + 0 * 64 + g] += sv0;
    v[node * 192 + 1 * 64 + g] += sv1;
    v[node * 192 + 2 * 64 + g] += sv2;
}

// -------------------- readout: out = (einsum(v,wout) - pos) * scale -------
__global__ __launch_bounds__(64) void readout_kernel(
    const float* __restrict__ v, const float* __restrict__ pos,
    const float* __restrict__ wout, const float* __restrict__ scale,
    float* __restrict__ out)
{
    const int node = blockIdx.x;
    const int f = threadIdx.x;
    const float wf = wout[f];
    float p0 = v[node * 192 + 0 * 64 + f] * wf;
    float p1 = v[node * 192 + 1 * 64 + f] * wf;
    float p2 = v[node * 192 + 2 * 64 + f] * wf;
#pragma unroll
    for (int off = 32; off > 0; off >>= 1) {
        p0 += __shfl_down(p0, off, 64);
        p1 += __shfl_down(p1, off, 64);
        p2 += __shfl_down(p2, off, 64);
    }
    if (f == 0) {
        const float sc = scale[0];
        out[node * 3 + 0] = (p0 - pos[node * 3 + 0]) * sc;
        out[node * 3 + 1] = (p1 - pos[node * 3 + 1]) * sc;
        out[node * 3 + 2] = (p2 - pos[node * 3 + 2]) * sc;
    }
}

extern "C" void kernel_launch(void* const* d_in, const int* in_sizes, int n_in,
                              void* d_out, int out_size, void* d_ws, size_t ws_size,
                              hipStream_t stream) {
    const float* pos     = (const float*)d_in[0];
    const int*   species = (const int*)  d_in[1];
    const float* glob    = (const float*)d_in[2];
    const float* embed   = (const float*)d_in[3];
    const float* glob_w  = (const float*)d_in[4];
    const float* rbf_w1  = (const float*)d_in[5];   // [2][8][64]
    const float* rbf_b1  = (const float*)d_in[6];   // [2][64]
    const float* rbf_w2  = (const float*)d_in[7];   // [2][64][192]
    const float* ws      = (const float*)d_in[8];   // [2][64][64]
    const float* wv      = (const float*)d_in[9];   // [2][64][64]
    const float* wout    = (const float*)d_in[10];  // [64]
    const float* scale   = (const float*)d_in[11];  // [1]

    float* wsf   = (float*)d_ws;
    float* s     = wsf;                 // 32*128*64      = 262144
    float* v     = wsf + 262144;        // 32*128*3*64    = 786432
    float* aggs  = wsf + 1048576;       // 262144
    float* aggv  = wsf + 1310720;       // 786432
    float* out   = (float*)d_out;

    init_kernel<<<dim3(BB * NN), 64, 0, stream>>>(species, glob, embed, glob_w, s, v);
    for (int l = 0; l < 2; ++l) {
        msg_kernel<<<dim3(NN, BB), 256, 0, stream>>>(
            pos, s, v,
            rbf_w1 + l * 8 * 64, rbf_b1 + l * 64, rbf_w2 + l * 64 * 192,
            aggs, aggv);
        update_kernel<<<dim3(BB * NN), 64, 0, stream>>>(
            aggs, aggv, ws + l * 64 * 64, wv + l * 64 * 64, s, v);
    }
    readout_kernel<<<dim3(BB * NN), 64, 0, stream>>>(v, pos, wout, scale, out);
}

// Round 2
// 202.644 us; speedup vs baseline: 3.9440x; 3.9440x over previous
//
#include <hip/hip_runtime.h>
#include <hip/hip_bf16.h>

// MACE-like GNN on MI355X — MFMA version.
// B=32, N=128, F=64, N_RBF=8, H_R=64, L=2.
// Per (b, i) block: hid[128x64]@W2[64x192] on matrix cores, messages on VALU.

#define NN 128
#define BB 32
#define FF 64

using f32x4  = __attribute__((ext_vector_type(4))) float;
using short8 = __attribute__((ext_vector_type(8))) short;

__device__ __forceinline__ unsigned short f2bf(float x) {
    unsigned int u = __float_as_uint(x);
    u += 0x7fff + ((u >> 16) & 1);          // round-nearest-even
    return (unsigned short)(u >> 16);
}

// -------------------- init: s = embed[species] + glob @ glob_w -------------
__global__ __launch_bounds__(256) void init_kernel(
    const int* __restrict__ species, const float* __restrict__ glob,
    const float* __restrict__ embed, const float* __restrict__ glob_w,
    float* __restrict__ s)
{
    const int node = blockIdx.x * 4 + (threadIdx.x >> 6);   // b*128 + n
    const int b = node >> 7;
    const int f = threadIdx.x & 63;
    const int sp = species[node];
    float acc = embed[sp * FF + f];
#pragma unroll
    for (int k = 0; k < 16; ++k)
        acc = fmaf(glob[b * 16 + k], glob_w[k * FF + f], acc);
    s[node * FF + f] = acc;
}

// -------------------- fused message+agg+update (+readout for LAYER==1) ----
// grid (128 receivers, 32 batch), block 256 = 4 waves.
// wave w owns channels f in [16w, 16w+16).
template<int LAYER>
__global__ __launch_bounds__(256) void msg_kernel(
    const float* __restrict__ pos,     // [B][N][3]
    const float* __restrict__ s_in,    // [B][N][F]
    const float* __restrict__ v_in,    // [B][N][3][F]  (unused when LAYER==0)
    const float* __restrict__ w1,      // [8][64]
    const float* __restrict__ b1,      // [64]
    const float* __restrict__ w2,      // [64][192]
    const float* __restrict__ ws_w,    // [64][64]
    const float* __restrict__ wv_w,    // [64][64]
    const float* __restrict__ wout,    // [64]
    const float* __restrict__ scale,   // [1]
    float* __restrict__ s_out,         // LAYER==0 only
    float* __restrict__ v_out,         // LAYER==0 only
    float* __restrict__ out)           // LAYER==1 only
{
    __shared__ unsigned short hid_lds[NN * 64];   // 16 KB, XOR-swizzled rows
    __shared__ float unit_lds[NN][4];
    __shared__ float d_lds[NN];
    __shared__ float agg_lds[4][64];

    const int i = blockIdx.x;
    const int b = blockIdx.y;
    const int t = threadIdx.x;
    const int w = t >> 6;          // wave
    const int l = t & 63;          // lane
    const int node = b * NN + i;
    const float* pb = pos + b * NN * 3;

    // ---- B fragments: W2 columns for this wave's 16 channels, r1/r2/r3 ----
    // b-frag layout (16x16x32): lane holds B[k=(l>>4)*8+e][col=l&15]
    short8 bfrag[3][2];
#pragma unroll
    for (int nt = 0; nt < 3; ++nt) {
#pragma unroll
        for (int ks = 0; ks < 2; ++ks) {
            const int col = nt * 64 + w * 16 + (l & 15);
            const int hb  = ks * 32 + (l >> 4) * 8;
            short8 bv;
#pragma unroll
            for (int e = 0; e < 8; ++e)
                bv[e] = (short)f2bf(w2[(hb + e) * 192 + col]);
            bfrag[nt][ks] = bv;
        }
    }

    // ---- phase A1: per-edge distance + unit vector ----
    if (t < NN) {
        const int j = t;
        const float dx = pb[i * 3 + 0] - pb[j * 3 + 0];
        const float dy = pb[i * 3 + 1] - pb[j * 3 + 1];
        const float dz = pb[i * 3 + 2] - pb[j * 3 + 2];
        const float d2 = fmaf(dx, dx, fmaf(dy, dy, fmaf(dz, dz, 1e-12f)));
        const float inv = rsqrtf(d2);
        d_lds[j] = d2 * inv;
        unit_lds[j][0] = dx * inv;
        unit_lds[j][1] = dy * inv;
        unit_lds[j][2] = dz * inv;
    }
    __syncthreads();

    // ---- phase A2: hid[j][h] = silu(phi(d_j) @ W1 + b1), bf16 -> LDS ----
    {
        const int hc = t & 7;          // h-chunk (8 units)
        const int h0 = hc * 8;
        const int jb = t >> 3;         // 0..31
        float w1r[8][8];
#pragma unroll
        for (int r = 0; r < 8; ++r) {
            const float4 a0 = *(const float4*)(w1 + r * 64 + h0);
            const float4 a1 = *(const float4*)(w1 + r * 64 + h0 + 4);
            w1r[r][0] = a0.x; w1r[r][1] = a0.y; w1r[r][2] = a0.z; w1r[r][3] = a0.w;
            w1r[r][4] = a1.x; w1r[r][5] = a1.y; w1r[r][6] = a1.z; w1r[r][7] = a1.w;
        }
        float b1r[8];
        {
            const float4 c0 = *(const float4*)(b1 + h0);
            const float4 c1 = *(const float4*)(b1 + h0 + 4);
            b1r[0] = c0.x; b1r[1] = c0.y; b1r[2] = c0.z; b1r[3] = c0.w;
            b1r[4] = c1.x; b1r[5] = c1.y; b1r[6] = c1.z; b1r[7] = c1.w;
        }
        const float inv2w2 = 1.28f;    // 1/(2*0.625^2)
#pragma unroll
        for (int it = 0; it < 4; ++it) {
            const int j = jb + it * 32;
            const float d = d_lds[j];
            float phi[8];
#pragma unroll
            for (int r = 0; r < 8; ++r) {
                const float td = d - (float)r * (5.0f / 7.0f);
                phi[r] = __expf(-td * td * inv2w2);
            }
            short8 hv;
#pragma unroll
            for (int e = 0; e < 8; ++e) {
                float acc = b1r[e];
#pragma unroll
                for (int r = 0; r < 8; ++r) acc = fmaf(phi[r], w1r[r][e], acc);
                const float sv = acc / (1.0f + __expf(-acc));
                hv[e] = (j == i) ? (short)0 : (short)f2bf(sv);
            }
            const int byte = j * 128 + ((h0 * 2) ^ ((j & 7) << 4));
            *(short8*)((char*)hid_lds + byte) = hv;
        }
    }
    __syncthreads();

    // ---- phase B: rw = hid @ W2sel via MFMA 16x16x32 bf16 ----
    // a-frag: lane holds A[row=mt*16+(l&15)][k=ks*32+(l>>4)*8+e]
    // acc (C/D): lane holds D[row=mt*16+(l>>4)*4+reg][col=(l&15)]
    f32x4 acc[3][8];
#pragma unroll
    for (int nt = 0; nt < 3; ++nt)
#pragma unroll
        for (int mt = 0; mt < 8; ++mt)
            acc[nt][mt] = (f32x4){0.f, 0.f, 0.f, 0.f};

#pragma unroll
    for (int ks = 0; ks < 2; ++ks) {
        short8 afr[8];
#pragma unroll
        for (int mt = 0; mt < 8; ++mt) {
            const int j = mt * 16 + (l & 15);
            const int byte = j * 128 + ((ks * 64 + (l >> 4) * 16) ^ ((j & 7) << 4));
            afr[mt] = *(const short8*)((const char*)hid_lds + byte);
        }
#pragma unroll
        for (int mt = 0; mt < 8; ++mt)
#pragma unroll
            for (int nt = 0; nt < 3; ++nt)
                acc[nt][mt] = __builtin_amdgcn_mfma_f32_16x16x32_bf16(
                    afr[mt], bfrag[nt][ks], acc[nt][mt], 0, 0, 0);
    }

    // ---- phase C: messages + aggregation over j (all within this wave) ----
    const int f    = w * 16 + (l & 15);
    const int jsub = (l >> 4) * 4;
    float accs = 0.f, av0 = 0.f, av1 = 0.f, av2 = 0.f;
    const float* sb = s_in + b * NN * FF;
    const float* vb = (LAYER > 0) ? (v_in + b * NN * 192) : nullptr;
#pragma unroll
    for (int mt = 0; mt < 8; ++mt) {
#pragma unroll
        for (int reg = 0; reg < 4; ++reg) {
            const int j  = mt * 16 + jsub + reg;
            const float r1 = acc[0][mt][reg];
            const float r2 = acc[1][mt][reg];
            const float r3 = acc[2][mt][reg];
            const float sj = sb[j * FF + f];
            const float r3s = r3 * sj;
            accs = fmaf(r1, sj, accs);
            av0 = fmaf(r3s, unit_lds[j][0], av0);
            av1 = fmaf(r3s, unit_lds[j][1], av1);
            av2 = fmaf(r3s, unit_lds[j][2], av2);
            if (LAYER > 0) {
                av0 = fmaf(r2, vb[j * 192 +   0 + f], av0);
                av1 = fmaf(r2, vb[j * 192 +  64 + f], av1);
                av2 = fmaf(r2, vb[j * 192 + 128 + f], av2);
            }
        }
    }
    accs += __shfl_xor(accs, 16, 64); accs += __shfl_xor(accs, 32, 64);
    av0  += __shfl_xor(av0, 16, 64);  av0  += __shfl_xor(av0, 32, 64);
    av1  += __shfl_xor(av1, 16, 64);  av1  += __shfl_xor(av1, 32, 64);
    av2  += __shfl_xor(av2, 16, 64);  av2  += __shfl_xor(av2, 32, 64);
    if ((l & 63) < 16 && l < 16) {
        const float invn = 1.0f / 127.0f;
        agg_lds[0][f] = accs * invn;
        agg_lds[1][f] = av0 * invn;
        agg_lds[2][f] = av1 * invn;
        agg_lds[3][f] = av2 * invn;
    }
    __syncthreads();

    // ---- tail: node update (+ readout for last layer) ----
    const int g = l;
    if (LAYER == 0) {
        if (w == 0) {
            float a = s_in[node * FF + g];
#pragma unroll
            for (int ff = 0; ff < 64; ++ff)
                a = fmaf(agg_lds[0][ff], ws_w[ff * 64 + g], a);
            s_out[node * FF + g] = a;
        } else {
            const int d = w - 1;
            float a = 0.f;
#pragma unroll
            for (int ff = 0; ff < 64; ++ff)
                a = fmaf(agg_lds[1 + d][ff], wv_w[ff * 64 + g], a);
            v_out[node * 192 + d * 64 + g] = a;
        }
    } else {
        if (w > 0) {
            const int d = w - 1;
            float a = v_in[node * 192 + d * 64 + g];
#pragma unroll
            for (int ff = 0; ff < 64; ++ff)
                a = fmaf(agg_lds[1 + d][ff], wv_w[ff * 64 + g], a);
            float p = a * wout[g];
#pragma unroll
            for (int off = 1; off < 64; off <<= 1)
                p += __shfl_xor(p, off, 64);
            if (l == 0)
                out[node * 3 + d] = (p - pos[node * 3 + d]) * scale[0];
        }
    }
}

extern "C" void kernel_launch(void* const* d_in, const int* in_sizes, int n_in,
                              void* d_out, int out_size, void* d_ws, size_t ws_size,
                              hipStream_t stream) {
    const float* pos     = (const float*)d_in[0];
    const int*   species = (const int*)  d_in[1];
    const float* glob    = (const float*)d_in[2];
    const float* embed   = (const float*)d_in[3];
    const float* glob_w  = (const float*)d_in[4];
    const float* rbf_w1  = (const float*)d_in[5];   // [2][8][64]
    const float* rbf_b1  = (const float*)d_in[6];   // [2][64]
    const float* rbf_w2  = (const float*)d_in[7];   // [2][64][192]
    const float* ws      = (const float*)d_in[8];   // [2][64][64]
    const float* wv      = (const float*)d_in[9];   // [2][64][64]
    const float* wout    = (const float*)d_in[10];  // [64]
    const float* scale   = (const float*)d_in[11];  // [1]

    float* wsf = (float*)d_ws;
    float* s0  = wsf;                  // 32*128*64   = 262144
    float* s1  = wsf + 262144;         // 262144
    float* v1  = wsf + 524288;         // 32*128*3*64 = 786432
    float* outp = (float*)d_out;

    init_kernel<<<dim3(BB * NN / 4), 256, 0, stream>>>(species, glob, embed, glob_w, s0);

    msg_kernel<0><<<dim3(NN, BB), 256, 0, stream>>>(
        pos, s0, nullptr,
        rbf_w1, rbf_b1, rbf_w2, ws, wv, wout, scale,
        s1, v1, nullptr);

    msg_kernel<1><<<dim3(NN, BB), 256, 0, stream>>>(
        pos, s1, v1,
        rbf_w1 + 8 * 64, rbf_b1 + 64, rbf_w2 + 64 * 192,
        ws + 64 * 64, wv + 64 * 64, wout, scale,
        nullptr, nullptr, outp);
}

// Round 3
// 113.671 us; speedup vs baseline: 7.0311x; 1.7827x over previous
//
#include <hip/hip_runtime.h>
#include <hip/hip_bf16.h>

// MACE-like GNN on MI355X — MFMA version, fused B/C pipeline per j-tile.
// B=32, N=128, F=64, N_RBF=8, H_R=64, L=2.

#define NN 128
#define BB 32
#define FF 64

using f32x4  = __attribute__((ext_vector_type(4))) float;
using short8 = __attribute__((ext_vector_type(8))) short;

__device__ __forceinline__ unsigned short f2bf(float x) {
    unsigned int u = __float_as_uint(x);
    u += 0x7fff + ((u >> 16) & 1);          // round-nearest-even
    return (unsigned short)(u >> 16);
}

// -------------------- init: s = embed[species] + glob @ glob_w -------------
__global__ __launch_bounds__(256) void init_kernel(
    const int* __restrict__ species, const float* __restrict__ glob,
    const float* __restrict__ embed, const float* __restrict__ glob_w,
    float* __restrict__ s)
{
    const int node = blockIdx.x * 4 + (threadIdx.x >> 6);   // b*128 + n
    const int b = node >> 7;
    const int f = threadIdx.x & 63;
    const int sp = species[node];
    float acc = embed[sp * FF + f];
#pragma unroll
    for (int k = 0; k < 16; ++k)
        acc = fmaf(glob[b * 16 + k], glob_w[k * FF + f], acc);
    s[node * FF + f] = acc;
}

// -------------------- fused message+agg+update (+readout for LAYER==1) ----
// grid (128 receivers, 32 batch), block 256 = 4 waves.
// wave w owns channels f in [16w, 16w+16).
template<int LAYER>
__global__ __launch_bounds__(256, 4) void msg_kernel(
    const float* __restrict__ pos,     // [B][N][3]
    const float* __restrict__ s_in,    // [B][N][F]
    const float* __restrict__ v_in,    // [B][N][3][F]  (unused when LAYER==0)
    const float* __restrict__ w1,      // [8][64]
    const float* __restrict__ b1,      // [64]
    const float* __restrict__ w2,      // [64][192]
    const float* __restrict__ ws_w,    // [64][64]
    const float* __restrict__ wv_w,    // [64][64]
    const float* __restrict__ wout,    // [64]
    const float* __restrict__ scale,   // [1]
    float* __restrict__ s_out,         // LAYER==0 only
    float* __restrict__ v_out,         // LAYER==0 only
    float* __restrict__ out)           // LAYER==1 only
{
    __shared__ unsigned short hid_lds[NN * 64];   // 16 KB, XOR-swizzled rows
    __shared__ float unit_lds[NN][4];
    __shared__ float d_lds[NN];
    __shared__ float agg_lds[4][64];

    const int i = blockIdx.x;
    const int b = blockIdx.y;
    const int t = threadIdx.x;
    const int w = t >> 6;          // wave
    const int l = t & 63;          // lane
    const int node = b * NN + i;
    const float* pb = pos + b * NN * 3;

    // ---- phase A1: per-edge distance + unit vector ----
    if (t < NN) {
        const int j = t;
        const float dx = pb[i * 3 + 0] - pb[j * 3 + 0];
        const float dy = pb[i * 3 + 1] - pb[j * 3 + 1];
        const float dz = pb[i * 3 + 2] - pb[j * 3 + 2];
        const float d2 = fmaf(dx, dx, fmaf(dy, dy, fmaf(dz, dz, 1e-12f)));
        const float inv = rsqrtf(d2);
        d_lds[j] = d2 * inv;
        unit_lds[j][0] = dx * inv;
        unit_lds[j][1] = dy * inv;
        unit_lds[j][2] = dz * inv;
    }
    __syncthreads();

    // ---- phase A2: hid[j][h] = silu(phi(d_j) @ W1 + b1), bf16 -> LDS ----
    {
        const int hc = t & 7;          // h-chunk (8 units)
        const int h0 = hc * 8;
        const int jb = t >> 3;         // 0..31
        float w1r[8][8];
#pragma unroll
        for (int r = 0; r < 8; ++r) {
            const float4 a0 = *(const float4*)(w1 + r * 64 + h0);
            const float4 a1 = *(const float4*)(w1 + r * 64 + h0 + 4);
            w1r[r][0] = a0.x; w1r[r][1] = a0.y; w1r[r][2] = a0.z; w1r[r][3] = a0.w;
            w1r[r][4] = a1.x; w1r[r][5] = a1.y; w1r[r][6] = a1.z; w1r[r][7] = a1.w;
        }
        float b1r[8];
        {
            const float4 c0 = *(const float4*)(b1 + h0);
            const float4 c1 = *(const float4*)(b1 + h0 + 4);
            b1r[0] = c0.x; b1r[1] = c0.y; b1r[2] = c0.z; b1r[3] = c0.w;
            b1r[4] = c1.x; b1r[5] = c1.y; b1r[6] = c1.z; b1r[7] = c1.w;
        }
        const float inv2w2 = 1.28f;    // 1/(2*0.625^2)
#pragma unroll
        for (int it = 0; it < 4; ++it) {
            const int j = jb + it * 32;
            const float d = d_lds[j];
            float phi[8];
#pragma unroll
            for (int r = 0; r < 8; ++r) {
                const float td = d - (float)r * (5.0f / 7.0f);
                phi[r] = __expf(-td * td * inv2w2);
            }
            short8 hv;
#pragma unroll
            for (int e = 0; e < 8; ++e) {
                float acc = b1r[e];
#pragma unroll
                for (int r = 0; r < 8; ++r) acc = fmaf(phi[r], w1r[r][e], acc);
                const float sv = acc / (1.0f + __expf(-acc));
                hv[e] = (j == i) ? (short)0 : (short)f2bf(sv);
            }
            const int byte = j * 128 + ((h0 * 2) ^ ((j & 7) << 4));
            *(short8*)((char*)hid_lds + byte) = hv;
        }
    }
    __syncthreads();

    // ---- B fragments: W2 columns for this wave's 16 channels, r1/r2/r3 ----
    // (loaded after A2 so the 24 regs don't add to A2's register peak)
    short8 bfrag[3][2];
#pragma unroll
    for (int nt = 0; nt < 3; ++nt) {
#pragma unroll
        for (int ks = 0; ks < 2; ++ks) {
            const int col = nt * 64 + w * 16 + (l & 15);
            const int hb  = ks * 32 + (l >> 4) * 8;
            short8 bv;
#pragma unroll
            for (int e = 0; e < 8; ++e)
                bv[e] = (short)f2bf(w2[(hb + e) * 192 + col]);
            bfrag[nt][ks] = bv;
        }
    }

    // ---- fused phase B+C: per 16-row j-tile, MFMA then consume ----
    const int f    = w * 16 + (l & 15);
    const int jsub = (l >> 4) * 4;
    const float* sb = s_in + b * NN * FF;
    const float* vb = (LAYER > 0) ? (v_in + b * NN * 192) : nullptr;

    float accs = 0.f, av0 = 0.f, av1 = 0.f, av2 = 0.f;

    // prefetch tile 0's s/v into registers
    float sP[4], v0P[4], v1P[4], v2P[4];
#pragma unroll
    for (int reg = 0; reg < 4; ++reg) {
        const int j = jsub + reg;
        sP[reg] = sb[j * FF + f];
        if (LAYER > 0) {
            v0P[reg] = vb[j * 192 +   0 + f];
            v1P[reg] = vb[j * 192 +  64 + f];
            v2P[reg] = vb[j * 192 + 128 + f];
        }
    }

#pragma unroll
    for (int mt = 0; mt < 8; ++mt) {
        // a-fragments for this 16-row tile (both K-slices)
        const int jA = mt * 16 + (l & 15);
        const int base = jA * 128;
        const int sw = (jA & 7) << 4;
        const short8 a0 = *(const short8*)((const char*)hid_lds + base + (((l >> 4) * 16 +  0) ^ sw));
        const short8 a1 = *(const short8*)((const char*)hid_lds + base + (((l >> 4) * 16 + 64) ^ sw));

        f32x4 c0 = (f32x4){0.f, 0.f, 0.f, 0.f};
        f32x4 c1 = (f32x4){0.f, 0.f, 0.f, 0.f};
        f32x4 c2 = (f32x4){0.f, 0.f, 0.f, 0.f};
        c0 = __builtin_amdgcn_mfma_f32_16x16x32_bf16(a0, bfrag[0][0], c0, 0, 0, 0);
        c0 = __builtin_amdgcn_mfma_f32_16x16x32_bf16(a1, bfrag[0][1], c0, 0, 0, 0);
        c1 = __builtin_amdgcn_mfma_f32_16x16x32_bf16(a0, bfrag[1][0], c1, 0, 0, 0);
        c1 = __builtin_amdgcn_mfma_f32_16x16x32_bf16(a1, bfrag[1][1], c1, 0, 0, 0);
        c2 = __builtin_amdgcn_mfma_f32_16x16x32_bf16(a0, bfrag[2][0], c2, 0, 0, 0);
        c2 = __builtin_amdgcn_mfma_f32_16x16x32_bf16(a1, bfrag[2][1], c2, 0, 0, 0);

        // prefetch next tile's s/v while MFMAs are in flight
        float sN[4], v0N[4], v1N[4], v2N[4];
        if (mt < 7) {
#pragma unroll
            for (int reg = 0; reg < 4; ++reg) {
                const int j = (mt + 1) * 16 + jsub + reg;
                sN[reg] = sb[j * FF + f];
                if (LAYER > 0) {
                    v0N[reg] = vb[j * 192 +   0 + f];
                    v1N[reg] = vb[j * 192 +  64 + f];
                    v2N[reg] = vb[j * 192 + 128 + f];
                }
            }
        }

        // consume this tile's messages (lane covers 4 j rows)
#pragma unroll
        for (int reg = 0; reg < 4; ++reg) {
            const int j  = mt * 16 + jsub + reg;
            const float r1 = c0[reg];
            const float r2 = c1[reg];
            const float r3 = c2[reg];
            const float sj = sP[reg];
            const float r3s = r3 * sj;
            accs = fmaf(r1, sj, accs);
            av0 = fmaf(r3s, unit_lds[j][0], av0);
            av1 = fmaf(r3s, unit_lds[j][1], av1);
            av2 = fmaf(r3s, unit_lds[j][2], av2);
            if (LAYER > 0) {
                av0 = fmaf(r2, v0P[reg], av0);
                av1 = fmaf(r2, v1P[reg], av1);
                av2 = fmaf(r2, v2P[reg], av2);
            }
        }
#pragma unroll
        for (int reg = 0; reg < 4; ++reg) {
            sP[reg] = sN[reg];
            if (LAYER > 0) { v0P[reg] = v0N[reg]; v1P[reg] = v1N[reg]; v2P[reg] = v2N[reg]; }
        }
    }

    accs += __shfl_xor(accs, 16, 64); accs += __shfl_xor(accs, 32, 64);
    av0  += __shfl_xor(av0, 16, 64);  av0  += __shfl_xor(av0, 32, 64);
    av1  += __shfl_xor(av1, 16, 64);  av1  += __shfl_xor(av1, 32, 64);
    av2  += __shfl_xor(av2, 16, 64);  av2  += __shfl_xor(av2, 32, 64);
    if (l < 16) {
        const float invn = 1.0f / 127.0f;
        agg_lds[0][f] = accs * invn;
        agg_lds[1][f] = av0 * invn;
        agg_lds[2][f] = av1 * invn;
        agg_lds[3][f] = av2 * invn;
    }
    __syncthreads();

    // ---- tail: node update (+ readout for last layer) ----
    const int g = l;
    if (LAYER == 0) {
        if (w == 0) {
            float a = s_in[node * FF + g];
#pragma unroll
            for (int ff = 0; ff < 64; ++ff)
                a = fmaf(agg_lds[0][ff], ws_w[ff * 64 + g], a);
            s_out[node * FF + g] = a;
        } else {
            const int d = w - 1;
            float a = 0.f;
#pragma unroll
            for (int ff = 0; ff < 64; ++ff)
                a = fmaf(agg_lds[1 + d][ff], wv_w[ff * 64 + g], a);
            v_out[node * 192 + d * 64 + g] = a;
        }
    } else {
        if (w > 0) {
            const int d = w - 1;
            float a = v_in[node * 192 + d * 64 + g];
#pragma unroll
            for (int ff = 0; ff < 64; ++ff)
                a = fmaf(agg_lds[1 + d][ff], wv_w[ff * 64 + g], a);
            float p = a * wout[g];
#pragma unroll
            for (int off = 1; off < 64; off <<= 1)
                p += __shfl_xor(p, off, 64);
            if (l == 0)
                out[node * 3 + d] = (p - pos[node * 3 + d]) * scale[0];
        }
    }
}

extern "C" void kernel_launch(void* const* d_in, const int* in_sizes, int n_in,
                              void* d_out, int out_size, void* d_ws, size_t ws_size,
                              hipStream_t stream) {
    const float* pos     = (const float*)d_in[0];
    const int*   species = (const int*)  d_in[1];
    const float* glob    = (const float*)d_in[2];
    const float* embed   = (const float*)d_in[3];
    const float* glob_w  = (const float*)d_in[4];
    const float* rbf_w1  = (const float*)d_in[5];   // [2][8][64]
    const float* rbf_b1  = (const float*)d_in[6];   // [2][64]
    const float* rbf_w2  = (const float*)d_in[7];   // [2][64][192]
    const float* ws      = (const float*)d_in[8];   // [2][64][64]
    const float* wv      = (const float*)d_in[9];   // [2][64][64]
    const float* wout    = (const float*)d_in[10];  // [64]
    const float* scale   = (const float*)d_in[11];  // [1]

    float* wsf = (float*)d_ws;
    float* s0  = wsf;                  // 32*128*64   = 262144
    float* s1  = wsf + 262144;         // 262144
    float* v1  = wsf + 524288;         // 32*128*3*64 = 786432
    float* outp = (float*)d_out;

    init_kernel<<<dim3(BB * NN / 4), 256, 0, stream>>>(species, glob, embed, glob_w, s0);

    msg_kernel<0><<<dim3(NN, BB), 256, 0, stream>>>(
        pos, s0, nullptr,
        rbf_w1, rbf_b1, rbf_w2, ws, wv, wout, scale,
        s1, v1, nullptr);

    msg_kernel<1><<<dim3(NN, BB), 256, 0, stream>>>(
        pos, s1, v1,
        rbf_w1 + 8 * 64, rbf_b1 + 64, rbf_w2 + 64 * 192,
        ws + 64 * 64, wv + 64 * 64, wout, scale,
        nullptr, nullptr, outp);
}

// Round 4
// 98.560 us; speedup vs baseline: 8.1091x; 1.1533x over previous
//
#include <hip/hip_runtime.h>
#include <hip/hip_bf16.h>

// MACE-like GNN on MI355X — MFMA + trimmed-VALU version.
// B=32, N=128, F=64, N_RBF=8, H_R=64, L=2.
// v workspace layout: [node][f][4] (float4 loads in phase C).

#define NN 128
#define BB 32
#define FF 64

using f32x4  = __attribute__((ext_vector_type(4))) float;
using short8 = __attribute__((ext_vector_type(8))) short;

__device__ __forceinline__ unsigned short f2bf(float x) {
    unsigned int u = __float_as_uint(x);
    u += 0x7fff + ((u >> 16) & 1);          // RNE (used for weights, one-time)
    return (unsigned short)(u >> 16);
}
__device__ __forceinline__ unsigned short f2bf_fast(float x) {
    return (unsigned short)((__float_as_uint(x) + 0x8000u) >> 16);
}

// -------------------- init: s = embed[species] + glob @ glob_w -------------
__global__ __launch_bounds__(256) void init_kernel(
    const int* __restrict__ species, const float* __restrict__ glob,
    const float* __restrict__ embed, const float* __restrict__ glob_w,
    float* __restrict__ s)
{
    const int node = blockIdx.x * 4 + (threadIdx.x >> 6);   // b*128 + n
    const int b = node >> 7;
    const int f = threadIdx.x & 63;
    const int sp = species[node];
    float acc = embed[sp * FF + f];
#pragma unroll
    for (int k = 0; k < 16; ++k)
        acc = fmaf(glob[b * 16 + k], glob_w[k * FF + f], acc);
    s[node * FF + f] = acc;
}

// -------------------- fused message+agg+update (+readout for LAYER==1) ----
// grid (128 receivers, 32 batch), block 256 = 4 waves.
// wave w owns channels f in [16w, 16w+16).
template<int LAYER>
__global__ __launch_bounds__(256, 4) void msg_kernel(
    const float* __restrict__ pos,     // [B][N][3]
    const float* __restrict__ s_in,    // [B][N][F]
    const float* __restrict__ v_in,    // [B][N][F][4]  (unused when LAYER==0)
    const float* __restrict__ w1,      // [8][64]
    const float* __restrict__ b1,      // [64]
    const float* __restrict__ w2,      // [64][192]
    const float* __restrict__ ws_w,    // [64][64]
    const float* __restrict__ wv_w,    // [64][64]
    const float* __restrict__ wout,    // [64]
    const float* __restrict__ scale,   // [1]
    float* __restrict__ s_out,         // LAYER==0 only
    float* __restrict__ v_out,         // LAYER==0 only, [B][N][F][4]
    float* __restrict__ out)           // LAYER==1 only
{
    __shared__ unsigned short hid_lds[NN * 64];   // 16 KB, XOR-swizzled rows
    __shared__ float4 unit_lds[NN];
    __shared__ float4 phiA[NN], phiB[NN];
    __shared__ float agg_lds[4][64];

    const int i = blockIdx.x;
    const int b = blockIdx.y;
    const int t = threadIdx.x;
    const int w = t >> 6;          // wave
    const int l = t & 63;          // lane
    const int node = b * NN + i;
    const float* pb = pos + b * NN * 3;

    // ---- phase A1: per-edge distance, unit vector, and RBF (once per j) ---
    if (t < NN) {
        const int j = t;
        const float dx = pb[i * 3 + 0] - pb[j * 3 + 0];
        const float dy = pb[i * 3 + 1] - pb[j * 3 + 1];
        const float dz = pb[i * 3 + 2] - pb[j * 3 + 2];
        const float d2 = fmaf(dx, dx, fmaf(dy, dy, fmaf(dz, dz, 1e-12f)));
        const float inv = __builtin_amdgcn_rsqf(d2);
        const float dd = d2 * inv;
        unit_lds[j] = make_float4(dx * inv, dy * inv, dz * inv, 0.0f);
        float ph[8];
#pragma unroll
        for (int r = 0; r < 8; ++r) {
            const float td = dd - (float)r * (5.0f / 7.0f);
            ph[r] = __expf(td * td * -1.28f);   // 1/(2*0.625^2) = 1.28
        }
        phiA[j] = make_float4(ph[0], ph[1], ph[2], ph[3]);
        phiB[j] = make_float4(ph[4], ph[5], ph[6], ph[7]);
    }
    __syncthreads();

    // ---- phase A2: hid[j][h] = silu(phi(d_j) @ W1 + b1), bf16 -> LDS ----
    {
        const int h0 = (t & 7) * 8;    // h-chunk (8 units)
        const int jb = t >> 3;         // 0..31
        float w1r[8][8];
#pragma unroll
        for (int r = 0; r < 8; ++r) {
            const float4 a0 = *(const float4*)(w1 + r * 64 + h0);
            const float4 a1 = *(const float4*)(w1 + r * 64 + h0 + 4);
            w1r[r][0] = a0.x; w1r[r][1] = a0.y; w1r[r][2] = a0.z; w1r[r][3] = a0.w;
            w1r[r][4] = a1.x; w1r[r][5] = a1.y; w1r[r][6] = a1.z; w1r[r][7] = a1.w;
        }
        float b1r[8];
        {
            const float4 c0 = *(const float4*)(b1 + h0);
            const float4 c1 = *(const float4*)(b1 + h0 + 4);
            b1r[0] = c0.x; b1r[1] = c0.y; b1r[2] = c0.z; b1r[3] = c0.w;
            b1r[4] = c1.x; b1r[5] = c1.y; b1r[6] = c1.z; b1r[7] = c1.w;
        }
#pragma unroll
        for (int it = 0; it < 4; ++it) {
            const int j = jb + it * 32;
            const float4 pA = phiA[j];
            const float4 pB = phiB[j];
            short8 hv;
#pragma unroll
            for (int e = 0; e < 8; ++e) {
                float acc = b1r[e];
                acc = fmaf(pA.x, w1r[0][e], acc);
                acc = fmaf(pA.y, w1r[1][e], acc);
                acc = fmaf(pA.z, w1r[2][e], acc);
                acc = fmaf(pA.w, w1r[3][e], acc);
                acc = fmaf(pB.x, w1r[4][e], acc);
                acc = fmaf(pB.y, w1r[5][e], acc);
                acc = fmaf(pB.z, w1r[6][e], acc);
                acc = fmaf(pB.w, w1r[7][e], acc);
                const float ex = __expf(-acc);
                const float sv = acc * __builtin_amdgcn_rcpf(1.0f + ex);
                hv[e] = (short)f2bf_fast(sv);
            }
            if (j == i) hv = (short8){0, 0, 0, 0, 0, 0, 0, 0};
            const int byte = j * 128 + ((h0 * 2) ^ ((j & 7) << 4));
            *(short8*)((char*)hid_lds + byte) = hv;
        }
    }
    __syncthreads();

    // ---- B fragments: W2 columns for this wave's 16 channels, r1/r2/r3 ----
    short8 bfrag[3][2];
#pragma unroll
    for (int nt = 0; nt < 3; ++nt) {
#pragma unroll
        for (int ks = 0; ks < 2; ++ks) {
            const int col = nt * 64 + w * 16 + (l & 15);
            const int hb  = ks * 32 + (l >> 4) * 8;
            short8 bv;
#pragma unroll
            for (int e = 0; e < 8; ++e)
                bv[e] = (short)f2bf(w2[(hb + e) * 192 + col]);
            bfrag[nt][ks] = bv;
        }
    }

    // ---- fused phase B+C: per 16-row j-tile, MFMA then consume ----
    const int f    = w * 16 + (l & 15);
    const int jsub = (l >> 4) * 4;
    const float* sb = s_in + b * NN * FF;
    const float4* vb4 = (LAYER > 0) ? ((const float4*)v_in) + b * NN * FF : nullptr;

    float accs = 0.f, av0 = 0.f, av1 = 0.f, av2 = 0.f;

    // prefetch tile 0's s/v into registers
    float sP[4]; float4 vP[4];
#pragma unroll
    for (int reg = 0; reg < 4; ++reg) {
        const int j = jsub + reg;
        sP[reg] = sb[j * FF + f];
        if (LAYER > 0) vP[reg] = vb4[j * FF + f];
    }

#pragma unroll
    for (int mt = 0; mt < 8; ++mt) {
        // a-fragments for this 16-row tile (both K-slices)
        const int jA = mt * 16 + (l & 15);
        const int base = jA * 128;
        const int sw = (jA & 7) << 4;
        const short8 a0 = *(const short8*)((const char*)hid_lds + base + (((l >> 4) * 16 +  0) ^ sw));
        const short8 a1 = *(const short8*)((const char*)hid_lds + base + (((l >> 4) * 16 + 64) ^ sw));

        f32x4 c0 = (f32x4){0.f, 0.f, 0.f, 0.f};
        f32x4 c1 = (f32x4){0.f, 0.f, 0.f, 0.f};
        f32x4 c2 = (f32x4){0.f, 0.f, 0.f, 0.f};
        c0 = __builtin_amdgcn_mfma_f32_16x16x32_bf16(a0, bfrag[0][0], c0, 0, 0, 0);
        c0 = __builtin_amdgcn_mfma_f32_16x16x32_bf16(a1, bfrag[0][1], c0, 0, 0, 0);
        c1 = __builtin_amdgcn_mfma_f32_16x16x32_bf16(a0, bfrag[1][0], c1, 0, 0, 0);
        c1 = __builtin_amdgcn_mfma_f32_16x16x32_bf16(a1, bfrag[1][1], c1, 0, 0, 0);
        c2 = __builtin_amdgcn_mfma_f32_16x16x32_bf16(a0, bfrag[2][0], c2, 0, 0, 0);
        c2 = __builtin_amdgcn_mfma_f32_16x16x32_bf16(a1, bfrag[2][1], c2, 0, 0, 0);

        // prefetch next tile's s/v while MFMAs are in flight
        float sN[4]; float4 vN[4];
        if (mt < 7) {
#pragma unroll
            for (int reg = 0; reg < 4; ++reg) {
                const int j = (mt + 1) * 16 + jsub + reg;
                sN[reg] = sb[j * FF + f];
                if (LAYER > 0) vN[reg] = vb4[j * FF + f];
            }
        }

        // consume this tile's messages (lane covers 4 j rows)
#pragma unroll
        for (int reg = 0; reg < 4; ++reg) {
            const int j  = mt * 16 + jsub + reg;
            const float r1 = c0[reg];
            const float r2 = c1[reg];
            const float r3 = c2[reg];
            const float sj = sP[reg];
            const float r3s = r3 * sj;
            const float4 u = unit_lds[j];
            accs = fmaf(r1, sj, accs);
            av0 = fmaf(r3s, u.x, av0);
            av1 = fmaf(r3s, u.y, av1);
            av2 = fmaf(r3s, u.z, av2);
            if (LAYER > 0) {
                av0 = fmaf(r2, vP[reg].x, av0);
                av1 = fmaf(r2, vP[reg].y, av1);
                av2 = fmaf(r2, vP[reg].z, av2);
            }
        }
#pragma unroll
        for (int reg = 0; reg < 4; ++reg) {
            sP[reg] = sN[reg];
            if (LAYER > 0) vP[reg] = vN[reg];
        }
    }

    accs += __shfl_xor(accs, 16, 64); accs += __shfl_xor(accs, 32, 64);
    av0  += __shfl_xor(av0, 16, 64);  av0  += __shfl_xor(av0, 32, 64);
    av1  += __shfl_xor(av1, 16, 64);  av1  += __shfl_xor(av1, 32, 64);
    av2  += __shfl_xor(av2, 16, 64);  av2  += __shfl_xor(av2, 32, 64);
    if (l < 16) {
        const float invn = 1.0f / 127.0f;
        agg_lds[0][f] = accs * invn;
        agg_lds[1][f] = av0 * invn;
        agg_lds[2][f] = av1 * invn;
        agg_lds[3][f] = av2 * invn;
    }
    __syncthreads();

    // ---- tail: node update (+ readout for last layer) ----
    const int g = l;
    if (LAYER == 0) {
        if (w == 0) {
            float a = s_in[node * FF + g];
#pragma unroll
            for (int ff = 0; ff < 64; ++ff)
                a = fmaf(agg_lds[0][ff], ws_w[ff * 64 + g], a);
            s_out[node * FF + g] = a;
        } else {
            const int d = w - 1;
            float a = 0.f;
#pragma unroll
            for (int ff = 0; ff < 64; ++ff)
                a = fmaf(agg_lds[1 + d][ff], wv_w[ff * 64 + g], a);
            v_out[(node * FF + g) * 4 + d] = a;
        }
    } else {
        if (w > 0) {
            const int d = w - 1;
            float a = v_in[(node * FF + g) * 4 + d];
#pragma unroll
            for (int ff = 0; ff < 64; ++ff)
                a = fmaf(agg_lds[1 + d][ff], wv_w[ff * 64 + g], a);
            float p = a * wout[g];
#pragma unroll
            for (int off = 1; off < 64; off <<= 1)
                p += __shfl_xor(p, off, 64);
            if (l == 0)
                out[node * 3 + d] = (p - pos[node * 3 + d]) * scale[0];
        }
    }
}

extern "C" void kernel_launch(void* const* d_in, const int* in_sizes, int n_in,
                              void* d_out, int out_size, void* d_ws, size_t ws_size,
                              hipStream_t stream) {
    const float* pos     = (const float*)d_in[0];
    const int*   species = (const int*)  d_in[1];
    const float* glob    = (const float*)d_in[2];
    const float* embed   = (const float*)d_in[3];
    const float* glob_w  = (const float*)d_in[4];
    const float* rbf_w1  = (const float*)d_in[5];   // [2][8][64]
    const float* rbf_b1  = (const float*)d_in[6];   // [2][64]
    const float* rbf_w2  = (const float*)d_in[7];   // [2][64][192]
    const float* ws      = (const float*)d_in[8];   // [2][64][64]
    const float* wv      = (const float*)d_in[9];   // [2][64][64]
    const float* wout    = (const float*)d_in[10];  // [64]
    const float* scale   = (const float*)d_in[11];  // [1]

    float* wsf = (float*)d_ws;
    float* s0  = wsf;                  // 32*128*64     = 262144
    float* s1  = wsf + 262144;         // 262144
    float* v1  = wsf + 524288;         // 32*128*64*4   = 1048576
    float* outp = (float*)d_out;

    init_kernel<<<dim3(BB * NN / 4), 256, 0, stream>>>(species, glob, embed, glob_w, s0);

    msg_kernel<0><<<dim3(NN, BB), 256, 0, stream>>>(
        pos, s0, nullptr,
        rbf_w1, rbf_b1, rbf_w2, ws, wv, wout, scale,
        s1, v1, nullptr);

    msg_kernel<1><<<dim3(NN, BB), 256, 0, stream>>>(
        pos, s1, v1,
        rbf_w1 + 8 * 64, rbf_b1 + 64, rbf_w2 + 64 * 192,
        ws + 64 * 64, wv + 64 * 64, wout, scale,
        nullptr, nullptr, outp);
}